// Round 3
// baseline (688.833 us; speedup 1.0000x reference)
//
#include <hip/hip_runtime.h>
#include <hip/hip_bf16.h>
#include <stdint.h>

#define NN 50000
#define NE 800000
#define NR 16
#define NP (NN * NR)                 // 800000 (rel,dst) bins
#define NB1 ((NP + 255) / 256)       // 3125
#define TN 32                        // fused tile: 32 nodes
#define NW 8                         // nodes aggregated per wave (TN/4)
#define NT32 ((NN + TN - 1) / TN)    // 1563 blocks -> ~6/CU grid, ~5/CU resident

typedef unsigned short u16;
typedef unsigned int u32;
typedef unsigned char u8;

typedef __bf16 bf16x8 __attribute__((ext_vector_type(8)));
typedef __bf16 bf16x2 __attribute__((ext_vector_type(2)));
typedef float f32x4 __attribute__((ext_vector_type(4)));

__device__ __forceinline__ u16 f2bf(float f) {
  u32 u = __float_as_uint(f);
  u = u + 0x7FFFu + ((u >> 16) & 1u);
  return (u16)(u >> 16);
}

__device__ __forceinline__ u32 pk2bf(float x, float y) {
#if __has_builtin(__builtin_amdgcn_cvt_pk_bf16_f32)
  bf16x2 r = __builtin_amdgcn_cvt_pk_bf16_f32(x, y);
  union { bf16x2 v; u32 u; } c;
  c.v = r;
  return c.u;
#else
  return (u32)f2bf(x) | ((u32)f2bf(y) << 16);
#endif
}

__device__ __forceinline__ float bflo(u32 w) { return __uint_as_float(w << 16); }
__device__ __forceinline__ float bfhi(u32 w) { return __uint_as_float(w & 0xFFFF0000u); }

// ---------------- edge sort by (rel, dst) — counting sort over NP bins ----------------
__global__ void hist_kernel(const int* __restrict__ dst, const int* __restrict__ rel,
                            int* __restrict__ counts) {
  int e = blockIdx.x * 256 + threadIdx.x;
  if (e < NE) atomicAdd(&counts[rel[e] * NN + dst[e]], 1);
}

__global__ void scan_partial(const int* __restrict__ counts, int* __restrict__ bsum) {
  __shared__ int buf[256];
  int t = threadIdx.x;
  int i = blockIdx.x * 256 + t;
  int v = (i < NP) ? counts[i] : 0;
  buf[t] = v;
  __syncthreads();
  for (int off = 1; off < 256; off <<= 1) {
    int x = buf[t];
    int y = (t >= off) ? buf[t - off] : 0;
    __syncthreads();
    buf[t] = x + y;
    __syncthreads();
  }
  if (t == 255) bsum[blockIdx.x] = buf[255];
}

// single block, 1024 threads, 4-serial each: scans NB1 (<=4096) block sums
__global__ void scan_mid(const int* __restrict__ bsum, int* __restrict__ boff,
                         int* __restrict__ total_out) {
  __shared__ int buf[1024];
  int t = threadIdx.x;
  int v[4];
  int sum = 0;
#pragma unroll
  for (int i = 0; i < 4; ++i) {
    int idx = t * 4 + i;
    v[i] = (idx < NB1) ? bsum[idx] : 0;
    sum += v[i];
  }
  buf[t] = sum;
  __syncthreads();
  for (int off = 1; off < 1024; off <<= 1) {
    int x = buf[t];
    int y = (t >= off) ? buf[t - off] : 0;
    __syncthreads();
    buf[t] = x + y;
    __syncthreads();
  }
  int excl = buf[t] - sum;
#pragma unroll
  for (int i = 0; i < 4; ++i) {
    int idx = t * 4 + i;
    if (idx < NB1) { boff[idx] = excl; excl += v[i]; }
  }
  if (t == 1023) *total_out = buf[1023];
}

__global__ void scan_final(const int* __restrict__ counts, const int* __restrict__ boff,
                           int* __restrict__ starts, int* __restrict__ cursor) {
  __shared__ int buf[256];
  int t = threadIdx.x;
  int i = blockIdx.x * 256 + t;
  int v = (i < NP) ? counts[i] : 0;
  buf[t] = v;
  __syncthreads();
  for (int off = 1; off < 256; off <<= 1) {
    int x = buf[t];
    int y = (t >= off) ? buf[t - off] : 0;
    __syncthreads();
    buf[t] = x + y;
    __syncthreads();
  }
  int s = boff[blockIdx.x] + buf[t] - v;
  if (i < NP) {
    starts[i] = s;
    cursor[i] = s;
  }
}

// sorted-order edge arrays: esd4 = dst<<16|src, rels = rel (u8), norm_s = norm
__global__ void scatter_kernel(const int* __restrict__ src, const int* __restrict__ dst,
                               const int* __restrict__ rel, const float* __restrict__ norm,
                               int* __restrict__ cursor, u32* __restrict__ esd4,
                               u8* __restrict__ rels, float* __restrict__ norm_s) {
  int e = blockIdx.x * 256 + threadIdx.x;
  if (e < NE) {
    int d = dst[e];
    int r = rel[e];
    int pos = atomicAdd(&cursor[r * NN + d], 1);
    esd4[pos] = ((u32)d << 16) | (u32)src[e];
    rels[pos] = (u8)r;
    norm_s[pos] = norm[e];
  }
}

// ---------------- weight convert: Wt[mat][d][k] = bf16(W[mat][k][d]) ----------------
// mats 0..15 = w0 rels, 16 = lw0, 17..32 = w1 rels, 33 = lw1
__global__ void convert_wt(const float* __restrict__ w0, const float* __restrict__ lw0,
                           const float* __restrict__ w1, const float* __restrict__ lw1,
                           u16* __restrict__ Wt) {
  int m = blockIdx.y;
  int idx = blockIdx.x * 256 + threadIdx.x; // 0..16383
  int d = idx >> 7, k = idx & 127;
  const float* s;
  if (m < 16) s = w0 + (size_t)m * 16384;
  else if (m == 16) s = lw0;
  else if (m < 33) s = w1 + (size_t)(m - 17) * 16384;
  else s = lw1;
  Wt[(size_t)m * 16384 + idx] = f2bf(s[k * 128 + d]);
}

// ---------------- h f32 -> bf16 (layer 0 input only) ----------------
__global__ void hconv_kernel(const float* __restrict__ h, u16* __restrict__ hbf) {
  int i = blockIdx.x * 256 + threadIdx.x; // float4 index
  float4 v = ((const float4*)h)[i];
  ushort4 u;
  u.x = f2bf(v.x); u.y = f2bf(v.y); u.z = f2bf(v.z); u.w = f2bf(v.w);
  ((ushort4*)hbf)[i] = u;
}

// ---------------- gate table: gates[r][n] = sigmoid(hbf[n] . gw[r]) ----------------
__global__ void gates_kernel(const u16* __restrict__ hbf, const float* __restrict__ gw,
                             float* __restrict__ gates) {
  __shared__ float hs[16 * 132];
  __shared__ float gws[16 * 132];
  int t = threadIdx.x;
  int n0 = blockIdx.x * 16;
#pragma unroll
  for (int i = 0; i < 2; ++i) {
    int f = t + 256 * i;            // 0..511
    int row = f >> 5, c4 = (f & 31) * 4;
    ushort4 u = *(const ushort4*)&hbf[(size_t)(n0 + row) * 128 + c4];
    hs[row * 132 + c4 + 0] = __uint_as_float((u32)u.x << 16);
    hs[row * 132 + c4 + 1] = __uint_as_float((u32)u.y << 16);
    hs[row * 132 + c4 + 2] = __uint_as_float((u32)u.z << 16);
    hs[row * 132 + c4 + 3] = __uint_as_float((u32)u.w << 16);
    *(float4*)&gws[row * 132 + c4] = *(const float4*)&gw[row * 128 + c4];
  }
  __syncthreads();
  int nl = t >> 4, r = t & 15;
  float s = 0.f;
#pragma unroll 8
  for (int k = 0; k < 128; ++k) s += hs[nl * 132 + k] * gws[r * 132 + k];
  gates[r * NN + n0 + nl] = 1.f / (1.f + __expf(-s));
}

// ---------------- per-edge coefficient: coef[e] = gate[rel][src] * norm ----------------
// Removes the dependent gate-gather from the fused kernel's critical path; gates table
// (3.2 MB) is L2-resident here. Same multiply order as before -> identical numerics.
__global__ void coef_kernel(const u32* __restrict__ esd4, const u8* __restrict__ rels,
                            const float* __restrict__ norm_s,
                            const float* __restrict__ gates, float* __restrict__ coef) {
  int e = blockIdx.x * 256 + threadIdx.x;
  if (e < NE) {
    u32 sn = esd4[e] & 0xFFFFu;
    int r = rels[e];
    coef[e] = gates[(size_t)r * NN + sn] * norm_s[e];
  }
}

// ---------------- FUSED aggregate + GEMM, v3 ----------------
// v2 residual: occupancy 29% (grid+VGPR capped) and a serial per-edge tail loop
// (~16 edges per wave-rel, batch-8 covered only the first 8). v3:
//  - TN=32 (1563 blocks, 17.4 KB LDS, lb(256,5)) -> ~5 blocks/CU resident
//  - masked batch-8: ALL edges take the batched path (clamped loads, wave-uniform
//    validity test) -> one vmcnt wait per 8 edges
//  - per-edge coef stream (precomputed): esd4+coef are sequential streams, only the
//    hbf row-gather remains dependent
template <int LAYER>
__global__ __launch_bounds__(256, 5)
void fused_kernel(const u16* __restrict__ hbf, const u32* __restrict__ esd4,
                  const float* __restrict__ coef, const int* __restrict__ starts,
                  const u16* __restrict__ Wt, const float* __restrict__ bias,
                  u16* __restrict__ hb_out, float* __restrict__ fout) {
  __shared__ u16 As[2][TN * 136];    // double-buffered node tile, pad +8 (272B stride)
  const u32* hbf32 = (const u32*)hbf;
  int t = threadIdx.x;
  int n0 = blockIdx.x * TN;
  int wave = t >> 6, lane = t & 63;
  int wd = wave * 32;                // wave owns d rows [wd, wd+32)
  int mrow = lane & 15, quad = lane >> 4;
  int vb = n0 + wave * NW;           // wave's aggregation node range [vb, vb+NW)
  int ve = vb + NW;
  if (ve > NN) ve = NN;
  bool aggok = vb < NN;

  f32x4 acc[2][2];
#pragma unroll
  for (int i = 0; i < 2; ++i)
#pragma unroll
    for (int j = 0; j < 2; ++j) acc[i][j] = (f32x4){0.f, 0.f, 0.f, 0.f};

  bf16x8 fw[4][2];

#define LOAD_FW(MAT)                                                          \
  {                                                                           \
    const u16* wmat = Wt + (size_t)(MAT) * 16384;                             \
    _Pragma("unroll")                                                         \
    for (int kk = 0; kk < 4; ++kk)                                            \
      _Pragma("unroll")                                                       \
      for (int i2 = 0; i2 < 2; ++i2)                                          \
        fw[kk][i2] = *(const bf16x8*)&wmat[(wd + i2 * 16 + mrow) * 128 +      \
                                           kk * 32 + quad * 8];               \
  }

  // Aggregate rel R's edges for nodes [vb, ve) into buffer B. Edges sorted by
  // (rel,dst): contiguous range, dst nondecreasing -> wave-uniform flush walk.
  // Masked batch-8: every edge goes through the batched (load-8, wait-once) path.
#define DO_AGG(B, S, E)                                                       \
  {                                                                           \
    u32* asp = (u32*)(&As[B][0]) + (wave * NW) * 68 + lane;                   \
    float a0 = 0.f, a1 = 0.f;                                                 \
    int cur = 0;                                                              \
    for (int j = (S); j < (E); j += 8) {                                      \
      u32 ds[8];                                                              \
      float cf[8];                                                            \
      _Pragma("unroll")                                                       \
      for (int i = 0; i < 8; ++i) {                                           \
        int ii = j + i;                                                       \
        ii = ii < (E) ? ii : (E) - 1;                                         \
        ds[i] = esd4[ii];                                                     \
        cf[i] = coef[ii];                                                     \
      }                                                                       \
      u32 w[8];                                                               \
      _Pragma("unroll")                                                       \
      for (int i = 0; i < 8; ++i)                                             \
        w[i] = hbf32[(ds[i] & 0xFFFFu) * 64u + (u32)lane];                    \
      _Pragma("unroll")                                                       \
      for (int i = 0; i < 8; ++i) {                                           \
        if (j + i < (E)) {                                                    \
          int local = (int)(ds[i] >> 16) - vb;                                \
          while (cur < local) {                                               \
            asp[cur * 68] = pk2bf(a0, a1);                                    \
            a0 = 0.f; a1 = 0.f; ++cur;                                        \
          }                                                                   \
          a0 = fmaf(cf[i], bflo(w[i]), a0);                                   \
          a1 = fmaf(cf[i], bfhi(w[i]), a1);                                   \
        }                                                                     \
      }                                                                       \
    }                                                                         \
    while (cur < NW) {                                                        \
      asp[cur * 68] = pk2bf(a0, a1);                                          \
      a0 = 0.f; a1 = 0.f; ++cur;                                              \
    }                                                                         \
  }

#define DO_MFMA(B)                                                            \
  _Pragma("unroll")                                                           \
  for (int kk = 0; kk < 4; ++kk) {                                            \
    int k0 = kk * 32 + quad * 8;                                              \
    bf16x8 fb[2];                                                             \
    _Pragma("unroll")                                                         \
    for (int j2 = 0; j2 < 2; ++j2)                                            \
      fb[j2] = *(const bf16x8*)&As[B][(j2 * 16 + mrow) * 136 + k0];           \
    _Pragma("unroll")                                                         \
    for (int i2 = 0; i2 < 2; ++i2)                                            \
      _Pragma("unroll")                                                       \
      for (int j2 = 0; j2 < 2; ++j2)                                          \
        acc[i2][j2] = __builtin_amdgcn_mfma_f32_16x16x32_bf16(                \
            fw[kk][i2], fb[j2], acc[i2][j2], 0, 0, 0);                        \
  }

  // rolling (s,e) prefetch: current rel's range preloaded one iteration ahead
  int sC = 0, eC = 0, sN = 0, eN = 0;
  if (aggok) { sC = starts[vb]; eC = starts[ve]; }             // rel 0
  LOAD_FW(0);
  if (aggok) { sN = starts[NN + vb]; eN = starts[NN + ve]; }   // rel 1
  DO_AGG(0, sC, eC);
  __syncthreads();

  for (int m = 0; m < 17; ++m) {
    DO_MFMA(m & 1);
    if (m < 16) LOAD_FW(m + 1);     // latency hides under the aggregation below
    if (m < 15) {
      int r = m + 1;
      sC = sN; eC = eN;
      if (aggok && r < 15) {        // prefetch rel r+1's range for next iter
        sN = starts[(r + 1) * NN + vb];
        eN = starts[(r + 1) * NN + ve];
      }
      DO_AGG((m + 1) & 1, sC, eC);
      __syncthreads();
    } else if (m == 15) {
      // mat 16 = self-loop: stage hbf node rows into buf0 (16&1 == 0)
#pragma unroll
      for (int i = 0; i < 2; ++i) {
        int u8i = t + 256 * i;      // 0..511 uint4 slots = 32 rows x 16
        int row = u8i >> 4, c8 = (u8i & 15) * 8;
        int n = n0 + row;
        int nc = n < NN ? n : NN - 1;   // clamp; garbage rows never stored
        *(uint4*)&As[0][row * 136 + c8] = *(const uint4*)&hbf[(size_t)nc * 128 + c8];
      }
      __syncthreads();
    }
    // m == 16: no barrier needed, fall through to epilogue
  }

  // epilogue: lane owns node n = n0 + j2*16 + mrow, d = wd + i2*16 + quad*4 .. +3
  float4 bvv[2];
#pragma unroll
  for (int i2 = 0; i2 < 2; ++i2)
    bvv[i2] = *(const float4*)&bias[wd + i2 * 16 + quad * 4];
#pragma unroll
  for (int j2 = 0; j2 < 2; ++j2) {
    int n = n0 + j2 * 16 + mrow;
    if (n < NN) {
#pragma unroll
      for (int i2 = 0; i2 < 2; ++i2) {
        int d0 = wd + i2 * 16 + quad * 4;
        float v0 = acc[i2][j2][0] + bvv[i2].x;
        float v1 = acc[i2][j2][1] + bvv[i2].y;
        float v2 = acc[i2][j2][2] + bvv[i2].z;
        float v3 = acc[i2][j2][3] + bvv[i2].w;
        if (LAYER == 0) {
          v0 = fmaxf(v0, 0.f); v1 = fmaxf(v1, 0.f);
          v2 = fmaxf(v2, 0.f); v3 = fmaxf(v3, 0.f);
          uint2 st;
          st.x = pk2bf(v0, v1);
          st.y = pk2bf(v2, v3);
          *(uint2*)&hb_out[(size_t)n * 128 + d0] = st;
        } else {
          float4 st = make_float4(v0, v1, v2, v3);
          *(float4*)&fout[(size_t)n * 128 + d0] = st;
        }
      }
    }
  }
#undef LOAD_FW
#undef DO_AGG
#undef DO_MFMA
}

// ---------------- host ----------------
extern "C" void kernel_launch(void* const* d_in, const int* in_sizes, int n_in,
                              void* d_out, int out_size, void* d_ws, size_t ws_size,
                              hipStream_t stream) {
  const float* h0   = (const float*)d_in[0];
  const float* norm = (const float*)d_in[1];
  const float* w0   = (const float*)d_in[2];
  const float* b0   = (const float*)d_in[3];
  const float* lw0  = (const float*)d_in[4];
  const float* gw0  = (const float*)d_in[5];
  const float* w1   = (const float*)d_in[6];
  const float* b1   = (const float*)d_in[7];
  const float* lw1  = (const float*)d_in[8];
  const float* gw1  = (const float*)d_in[9];
  const int*   src  = (const int*)d_in[10];
  const int*   dst  = (const int*)d_in[11];
  const int*   rel  = (const int*)d_in[12];
  float* out = (float*)d_out;

  char* p = (char*)d_ws;
  auto alloc = [&](size_t bytes) -> void* {
    void* q = (void*)p;
    p += (bytes + 255) & ~(size_t)255;
    return q;
  };
  u16*   Wt     = (u16*)alloc((size_t)34 * 16384 * 2);
  float* gates  = (float*)alloc((size_t)NR * NN * 4);
  u16*   hbf0   = (u16*)alloc((size_t)NN * 128 * 2);
  u16*   hbf1   = (u16*)alloc((size_t)NN * 128 * 2);
  int*   counts = (int*)alloc((size_t)NP * 4);
  int*   cursor = (int*)alloc((size_t)NP * 4);
  int*   starts = (int*)alloc((size_t)(NP + 1) * 4);
  int*   bsum   = (int*)alloc((size_t)NB1 * 4);
  int*   boff   = (int*)alloc((size_t)NB1 * 4);
  u32*   esd4   = (u32*)alloc((size_t)NE * 4);
  u8*    rels   = (u8*)alloc((size_t)NE);
  float* norm_s = (float*)alloc((size_t)NE * 4);
  float* coef   = (float*)alloc((size_t)NE * 4);

  // ---- sort edges by (rel, dst) — shared by both layers ----
  hipMemsetAsync(counts, 0, (size_t)NP * 4, stream);
  hist_kernel<<<NE / 256, 256, 0, stream>>>(dst, rel, counts);
  scan_partial<<<NB1, 256, 0, stream>>>(counts, bsum);
  scan_mid<<<1, 1024, 0, stream>>>(bsum, boff, starts + NP);
  scan_final<<<NB1, 256, 0, stream>>>(counts, boff, starts, cursor);
  scatter_kernel<<<NE / 256, 256, 0, stream>>>(src, dst, rel, norm, cursor,
                                               esd4, rels, norm_s);
  convert_wt<<<dim3(64, 34), 256, 0, stream>>>(w0, lw0, w1, lw1, Wt);
  hconv_kernel<<<NN * 32 / 256, 256, 0, stream>>>(h0, hbf0);

  // ---- layer 0 (relu, bf16 output) ----
  gates_kernel<<<NN / 16, 256, 0, stream>>>(hbf0, gw0, gates);
  coef_kernel<<<(NE + 255) / 256, 256, 0, stream>>>(esd4, rels, norm_s, gates, coef);
  fused_kernel<0><<<NT32, 256, 0, stream>>>(hbf0, esd4, coef, starts, Wt, b0,
                                            hbf1, nullptr);

  // ---- layer 1 (no relu, f32 output) ----
  gates_kernel<<<NN / 16, 256, 0, stream>>>(hbf1, gw1, gates);
  coef_kernel<<<(NE + 255) / 256, 256, 0, stream>>>(esd4, rels, norm_s, gates, coef);
  fused_kernel<1><<<NT32, 256, 0, stream>>>(hbf1, esd4, coef, starts,
                                            Wt + (size_t)17 * 16384, b1,
                                            nullptr, out);
}